// Round 1
// baseline (1295.127 us; speedup 1.0000x reference)
//
#include <hip/hip_runtime.h>
#include <stdint.h>

#define E_TOT 500000
#define BM 128
#define NTHREADS 512

typedef float f32x4 __attribute__((ext_vector_type(4)));
typedef short short8 __attribute__((ext_vector_type(8)));

__device__ __forceinline__ float b2f(ushort u) {
    union { uint32_t i; float f; } v; v.i = ((uint32_t)u) << 16; return v.f;
}
__device__ __forceinline__ ushort f2b(float f) {
    union { float f; uint32_t i; } v; v.f = f;
    uint32_t r = (v.i + 0x7FFFu + ((v.i >> 16) & 1u)) >> 16;
    return (ushort)r;
}
__device__ __forceinline__ float ldf(const void* p, int i, int f32m) {
    return f32m ? ((const float*)p)[i] : b2f(((const ushort*)p)[i]);
}

// ---- format detection: flags[0]=1 if float inputs are f32, flags[1]=1 if batch is int64 ----
__global__ void detect_fmt(const void* src, const void* batch, int* flags) {
    __shared__ int s_ok, s_nz;
    if (threadIdx.x == 0) { s_ok = 0; s_nz = 0; }
    __syncthreads();
    int t = threadIdx.x;
    if (t < 64) {
        float f = fabsf(b2f(((const ushort*)src)[2 * t]));
        if (f > 1e-3f && f < 1e2f) atomicAdd(&s_ok, 1);
    }
    int hv = ((const int*)batch)[2 * t + 1];
    if (hv != 0) atomicOr(&s_nz, 1);
    __syncthreads();
    if (t == 0) { flags[0] = (s_ok < 32) ? 1 : 0; flags[1] = (s_nz == 0) ? 1 : 0; }
}

// ---- prep: transpose weights -> bf16 [N][K], convert small params -> f32 ----
// reads are source-linear (coalesced); scattered 2B writes are absorbed by L2 (384KB total)
__global__ void prep(const int* __restrict__ flags,
                     const void* W1, const void* W2, const void* W3,
                     const void* Ww, const void* bw, const void* gw, const void* bew,
                     const void* b1, const void* g1, const void* be1,
                     const void* b2, const void* g2, const void* be2, const void* b3,
                     ushort* __restrict__ W1t, ushort* __restrict__ W2t,
                     ushort* __restrict__ W3t, float* __restrict__ params) {
    int f32m = flags[0];
    int id = blockIdx.x * 256 + threadIdx.x;
    if (id < 98304) {                     // W1 [384][256] -> W1t [256][384]
        int k = id >> 8, n = id & 255;
        W1t[n * 384 + k] = f2b(ldf(W1, id, f32m));
    } else if (id < 163840) {             // W2 [256][256] -> W2t [256][256]
        int t = id - 98304; int k = t >> 8, n = t & 255;
        W2t[n * 256 + k] = f2b(ldf(W2, t, f32m));
    } else if (id < 180224) {             // W3 [256][64] -> W3t [64][256]
        int t = id - 163840; int k = t >> 6, n = t & 63;
        W3t[n * 256 + k] = f2b(ldf(W3, t, f32m));
    } else if (id < 182464) {             // params -> f32
        int p = id - 180224;
        const void* sp; int off;
        if      (p < 256)  { sp = Ww;  off = p; }
        else if (p < 384)  { sp = bw;  off = p - 256; }
        else if (p < 512)  { sp = gw;  off = p - 384; }
        else if (p < 640)  { sp = bew; off = p - 512; }
        else if (p < 896)  { sp = b1;  off = p - 640; }
        else if (p < 1152) { sp = g1;  off = p - 896; }
        else if (p < 1408) { sp = be1; off = p - 1152; }
        else if (p < 1664) { sp = b2;  off = p - 1408; }
        else if (p < 1920) { sp = g2;  off = p - 1664; }
        else if (p < 2176) { sp = be2; off = p - 1920; }
        else               { sp = b3;  off = p - 2176; }
        params[p] = ldf(sp, off, f32m);
    }
}

// Barrier-free K-loop design:
//  - A fragments (layer1, bf16 mode): direct 16B global loads (HBM-streamed, lines fully consumed)
//  - B fragments: direct 16B global loads from bf16 W1t/W2t/W3t (L2-resident; each element
//    read once per block since waves own disjoint column quarters -> LDS staging dedups nothing)
//  - single 64KB LDS buffer xh[128][256] holds winding-tile, then h1, then h2 (phases separated
//    by the LN-epilogue barriers); XOR swizzle on 16B granules: g ^= row&7 kills the stride-4-dword
//    bank conflicts of the old 264-ushort htile.
//  - 7 barriers/block instead of ~60; LDS 80128B -> 2 blocks/CU (vs 1), launch_bounds caps VGPR=128.
__global__ __launch_bounds__(NTHREADS, 4) void fused_edge_mlp(
    const void* __restrict__ srcv, const void* __restrict__ destv,
    const void* __restrict__ eav, const void* __restrict__ uv,
    const int* __restrict__ bp, const void* __restrict__ windv,
    const int* __restrict__ flags, const float* __restrict__ params,
    const ushort* __restrict__ W1t, const ushort* __restrict__ W2t, const ushort* __restrict__ W3t,
    float* __restrict__ outp)
{
    __shared__ __align__(16) ushort xh[BM * 256];     // 64KB: wtile(cols 0..127) -> h1 -> h2
    __shared__ float s_ww0[128], s_ww1[128], s_bw[128], s_gw[128], s_bew[128];
    __shared__ float s_b1[256], s_g1[256], s_be1[256];
    __shared__ float s_b2[256], s_g2[256], s_be2[256];
    __shared__ float s_b3[64];
    __shared__ int   s_uoff[BM];
    __shared__ float s_red1[BM * 4], s_red2[BM * 4];
    __shared__ float s_mu[BM], s_rs[BM];

    const int tid  = threadIdx.x;
    const int base = blockIdx.x * BM;
    const int f32m = flags[0];
    const int i64m = flags[1];

    // ---- stage small params to LDS ----
    if (tid < 128) {
        s_ww0[tid] = params[tid];        s_ww1[tid] = params[128 + tid];
        s_bw[tid]  = params[256 + tid];  s_gw[tid]  = params[384 + tid];
        s_bew[tid] = params[512 + tid];
        int gr = base + tid; if (gr >= E_TOT) gr = E_TOT - 1;
        int bi = i64m ? bp[2 * gr] : bp[gr];
        s_uoff[tid] = bi * 64;
    } else if (tid < 384) {
        int j = tid - 128;
        s_b1[j] = params[640 + j];  s_g1[j] = params[896 + j];  s_be1[j] = params[1152 + j];
        s_b2[j] = params[1408 + j]; s_g2[j] = params[1664 + j]; s_be2[j] = params[1920 + j];
    } else if (tid < 448) {
        s_b3[tid - 384] = params[2176 + tid - 384];
    }
    __syncthreads();

    // ---- winding MLP: Linear(2->128) + LN + ReLU -> xh cols [0,128), swizzled bf16 ----
    {
        int r = tid >> 2, sub = tid & 3;
        int gr = base + r; if (gr >= E_TOT) gr = E_TOT - 1;
        float w0, w1;
        if (f32m) { const float* wp = (const float*)windv; w0 = wp[(long)gr * 2]; w1 = wp[(long)gr * 2 + 1]; }
        else      { const ushort* wp = (const ushort*)windv; w0 = b2f(wp[(long)gr * 2]); w1 = b2f(wp[(long)gr * 2 + 1]); }
        float s1 = 0.f, s2 = 0.f;
        float vv[32];
        #pragma unroll
        for (int j0 = 0; j0 < 32; ++j0) {
            int j = sub * 32 + j0;
            float t = fmaf(w0, s_ww0[j], fmaf(w1, s_ww1[j], s_bw[j]));
            vv[j0] = t; s1 += t; s2 += t * t;
        }
        s1 += __shfl_xor(s1, 1); s2 += __shfl_xor(s2, 1);
        s1 += __shfl_xor(s1, 2); s2 += __shfl_xor(s2, 2);
        float mu  = s1 * (1.f / 128.f);
        float var = s2 * (1.f / 128.f) - mu * mu;
        float rs  = rsqrtf(var + 1e-5f);
        #pragma unroll
        for (int j0 = 0; j0 < 32; ++j0) {
            int j = sub * 32 + j0;
            float t = (vv[j0] - mu) * rs * s_gw[j] + s_bew[j];
            xh[r * 256 + ((((j >> 3) ^ (r & 7))) << 3) + (j & 7)] = f2b(fmaxf(t, 0.f));
        }
    }
    __syncthreads();

    // ---- wave/lane geometry ----
    const int lane = tid & 63;
    const int wav  = tid >> 6;
    const int q    = lane >> 4, n16 = lane & 15;
    const int rh   = wav >> 2,  cq  = wav & 3;
    const int rowbase = rh * 64, colbase = cq * 64;
    const int koff = q * 8;

    int rowA[4], grA[4], uofA[4];
    #pragma unroll
    for (int rt = 0; rt < 4; ++rt) {
        int row = rowbase + rt * 16 + n16;
        rowA[rt] = row;
        int gr = base + row; if (gr >= E_TOT) gr = E_TOT - 1;
        grA[rt] = gr;
        uofA[rt] = s_uoff[row];
    }

    auto xh_frag = [&](int row, int colg) -> short8 {
        return *(const short8*)&xh[row * 256 + ((colg ^ (row & 7)) << 3)];
    };

    f32x4 acc[4][4];
    #pragma unroll
    for (int a = 0; a < 4; ++a)
        #pragma unroll
        for (int b = 0; b < 4; ++b) acc[a][b] = (f32x4){0.f, 0.f, 0.f, 0.f};

    // ---- Layer 1: x[128,384] @ W1 -> [128,256], no barriers ----
    const ushort* w1p[4];
    #pragma unroll
    for (int ct = 0; ct < 4; ++ct)
        w1p[ct] = W1t + (colbase + ct * 16 + n16) * 384 + koff;

    if (!f32m) {
        #pragma unroll
        for (int kc = 0; kc < 8; ++kc) {
            const int grp = kc >> 1, off = (kc & 1) * 32 + koff;
            short8 afr[4], bfr[4];
            #pragma unroll
            for (int rt = 0; rt < 4; ++rt) {
                const ushort* ap;
                if      (grp == 0) ap = (const ushort*)srcv  + (long)grA[rt] * 64 + off;
                else if (grp == 1) ap = (const ushort*)destv + (long)grA[rt] * 64 + off;
                else if (grp == 2) ap = (const ushort*)eav   + (long)grA[rt] * 64 + off;
                else               ap = (const ushort*)uv    + uofA[rt] + off;
                afr[rt] = *(const short8*)ap;
            }
            #pragma unroll
            for (int ct = 0; ct < 4; ++ct) bfr[ct] = *(const short8*)(w1p[ct] + kc * 32);
            #pragma unroll
            for (int rt = 0; rt < 4; ++rt)
                #pragma unroll
                for (int ct = 0; ct < 4; ++ct)
                    acc[rt][ct] = __builtin_amdgcn_mfma_f32_16x16x32_bf16(afr[rt], bfr[ct], acc[rt][ct], 0, 0, 0);
        }
    } else {
        #pragma unroll
        for (int kc = 0; kc < 8; ++kc) {
            const int grp = kc >> 1, off = (kc & 1) * 32 + koff;
            short8 afr[4], bfr[4];
            #pragma unroll
            for (int rt = 0; rt < 4; ++rt) {
                const float* ap;
                if      (grp == 0) ap = (const float*)srcv  + (long)grA[rt] * 64 + off;
                else if (grp == 1) ap = (const float*)destv + (long)grA[rt] * 64 + off;
                else if (grp == 2) ap = (const float*)eav   + (long)grA[rt] * 64 + off;
                else               ap = (const float*)uv    + uofA[rt] + off;
                float4 x0 = *(const float4*)ap, x1 = *(const float4*)(ap + 4);
                union { short8 v; ushort s[8]; } pk;
                pk.s[0] = f2b(x0.x); pk.s[1] = f2b(x0.y); pk.s[2] = f2b(x0.z); pk.s[3] = f2b(x0.w);
                pk.s[4] = f2b(x1.x); pk.s[5] = f2b(x1.y); pk.s[6] = f2b(x1.z); pk.s[7] = f2b(x1.w);
                afr[rt] = pk.v;
            }
            #pragma unroll
            for (int ct = 0; ct < 4; ++ct) bfr[ct] = *(const short8*)(w1p[ct] + kc * 32);
            #pragma unroll
            for (int rt = 0; rt < 4; ++rt)
                #pragma unroll
                for (int ct = 0; ct < 4; ++ct)
                    acc[rt][ct] = __builtin_amdgcn_mfma_f32_16x16x32_bf16(afr[rt], bfr[ct], acc[rt][ct], 0, 0, 0);
        }
    }
    // winding columns of x (from LDS)
    #pragma unroll
    for (int kc = 8; kc < 12; ++kc) {
        short8 afr[4], bfr[4];
        #pragma unroll
        for (int rt = 0; rt < 4; ++rt) afr[rt] = xh_frag(rowA[rt], (kc - 8) * 4 + q);
        #pragma unroll
        for (int ct = 0; ct < 4; ++ct) bfr[ct] = *(const short8*)(w1p[ct] + kc * 32);
        #pragma unroll
        for (int rt = 0; rt < 4; ++rt)
            #pragma unroll
            for (int ct = 0; ct < 4; ++ct)
                acc[rt][ct] = __builtin_amdgcn_mfma_f32_16x16x32_bf16(afr[rt], bfr[ct], acc[rt][ct], 0, 0, 0);
    }

    // ---- fused bias + LN + ReLU epilogue -> xh (swizzled bf16) ----
    auto ln_epilogue = [&](const float* bias, const float* gamma, const float* beta) {
        #pragma unroll
        for (int rt = 0; rt < 4; ++rt) {
            #pragma unroll
            for (int i = 0; i < 4; ++i) {
                float sv = 0.f, sq = 0.f;
                #pragma unroll
                for (int ct = 0; ct < 4; ++ct) {
                    float t = acc[rt][ct][i] + bias[colbase + ct * 16 + n16];
                    sv += t; sq += t * t;
                }
                #pragma unroll
                for (int m = 1; m < 16; m <<= 1) {
                    sv += __shfl_xor(sv, m); sq += __shfl_xor(sq, m);
                }
                if (n16 == 0) {
                    int row = rowbase + rt * 16 + q * 4 + i;
                    s_red1[row * 4 + cq] = sv; s_red2[row * 4 + cq] = sq;
                }
            }
        }
        __syncthreads();
        if (tid < BM) {
            float sv = s_red1[tid * 4] + s_red1[tid * 4 + 1] + s_red1[tid * 4 + 2] + s_red1[tid * 4 + 3];
            float sq = s_red2[tid * 4] + s_red2[tid * 4 + 1] + s_red2[tid * 4 + 2] + s_red2[tid * 4 + 3];
            float mu  = sv * (1.f / 256.f);
            float var = sq * (1.f / 256.f) - mu * mu;
            s_mu[tid] = mu; s_rs[tid] = rsqrtf(var + 1e-5f);
        }
        __syncthreads();
        #pragma unroll
        for (int rt = 0; rt < 4; ++rt) {
            #pragma unroll
            for (int ct = 0; ct < 4; ++ct) {
                int col = colbase + ct * 16 + n16;
                float bb = bias[col], gg = gamma[col], be = beta[col];
                #pragma unroll
                for (int i = 0; i < 4; ++i) {
                    int row = rowbase + rt * 16 + q * 4 + i;
                    float t = acc[rt][ct][i] + bb;
                    t = (t - s_mu[row]) * s_rs[row] * gg + be;
                    xh[row * 256 + ((((col >> 3) ^ (row & 7))) << 3) + (col & 7)] = f2b(fmaxf(t, 0.f));
                }
            }
        }
        __syncthreads();
    };
    ln_epilogue(s_b1, s_g1, s_be1);

    // ---- Layer 2: h1[128,256] @ W2 -> [128,256], no barriers in loop ----
    #pragma unroll
    for (int a = 0; a < 4; ++a)
        #pragma unroll
        for (int b = 0; b < 4; ++b) acc[a][b] = (f32x4){0.f, 0.f, 0.f, 0.f};
    const ushort* w2p[4];
    #pragma unroll
    for (int ct = 0; ct < 4; ++ct)
        w2p[ct] = W2t + (colbase + ct * 16 + n16) * 256 + koff;
    #pragma unroll
    for (int kc = 0; kc < 8; ++kc) {
        short8 afr[4], bfr[4];
        #pragma unroll
        for (int rt = 0; rt < 4; ++rt) afr[rt] = xh_frag(rowA[rt], kc * 4 + q);
        #pragma unroll
        for (int ct = 0; ct < 4; ++ct) bfr[ct] = *(const short8*)(w2p[ct] + kc * 32);
        #pragma unroll
        for (int rt = 0; rt < 4; ++rt)
            #pragma unroll
            for (int ct = 0; ct < 4; ++ct)
                acc[rt][ct] = __builtin_amdgcn_mfma_f32_16x16x32_bf16(afr[rt], bfr[ct], acc[rt][ct], 0, 0, 0);
    }
    ln_epilogue(s_b2, s_g2, s_be2);   // h2 overwrites h1 (dead after L2 MFMAs; barriers guard)

    // ---- Layer 3: h2[128,256] @ W3 -> out [128,64] (f32) ----
    // wave = 32-row group x 32-col half: minimizes duplicated W3 reads
    f32x4 acc3[2][2];
    #pragma unroll
    for (int a = 0; a < 2; ++a)
        #pragma unroll
        for (int b = 0; b < 2; ++b) acc3[a][b] = (f32x4){0.f, 0.f, 0.f, 0.f};
    const int rgrp = wav >> 1, chalf = wav & 1;
    int row3[2];
    #pragma unroll
    for (int rt = 0; rt < 2; ++rt) row3[rt] = rgrp * 32 + rt * 16 + n16;
    const ushort* w3p[2];
    #pragma unroll
    for (int ct = 0; ct < 2; ++ct)
        w3p[ct] = W3t + (chalf * 32 + ct * 16 + n16) * 256 + koff;
    #pragma unroll
    for (int kc = 0; kc < 8; ++kc) {
        short8 a3[2], b3r[2];
        #pragma unroll
        for (int rt = 0; rt < 2; ++rt) a3[rt] = xh_frag(row3[rt], kc * 4 + q);
        #pragma unroll
        for (int ct = 0; ct < 2; ++ct) b3r[ct] = *(const short8*)(w3p[ct] + kc * 32);
        #pragma unroll
        for (int rt = 0; rt < 2; ++rt)
            #pragma unroll
            for (int ct = 0; ct < 2; ++ct)
                acc3[rt][ct] = __builtin_amdgcn_mfma_f32_16x16x32_bf16(a3[rt], b3r[ct], acc3[rt][ct], 0, 0, 0);
    }
    #pragma unroll
    for (int rt = 0; rt < 2; ++rt) {
        #pragma unroll
        for (int ct = 0; ct < 2; ++ct) {
            int col = chalf * 32 + ct * 16 + n16;
            float bb = s_b3[col];
            #pragma unroll
            for (int i = 0; i < 4; ++i) {
                int row = rgrp * 32 + rt * 16 + q * 4 + i;
                int gr  = base + row;
                if (gr < E_TOT) outp[(long)gr * 64 + col] = acc3[rt][ct][i] + bb;
            }
        }
    }
}

extern "C" void kernel_launch(void* const* d_in, const int* in_sizes, int n_in,
                              void* d_out, int out_size, void* d_ws, size_t ws_size,
                              hipStream_t stream) {
    int*    flags  = (int*)d_ws;
    float*  params = (float*)((char*)d_ws + 16);
    ushort* W1t    = (ushort*)((char*)d_ws + 9216);     // [256][384]
    ushort* W2t    = W1t + 98304;                        // [256][256]
    ushort* W3t    = W2t + 65536;                        // [64][256]

    detect_fmt<<<1, 256, 0, stream>>>(d_in[0], d_in[4], flags);
    prep<<<713, 256, 0, stream>>>(flags,
        d_in[10], d_in[14], d_in[18],
        d_in[6], d_in[7], d_in[8], d_in[9],
        d_in[11], d_in[12], d_in[13],
        d_in[15], d_in[16], d_in[17], d_in[19],
        W1t, W2t, W3t, params);

    int nblocks = (E_TOT + BM - 1) / BM;   // 3907
    fused_edge_mlp<<<nblocks, NTHREADS, 0, stream>>>(
        d_in[0], d_in[1], d_in[2], d_in[3], (const int*)d_in[4], d_in[5],
        flags, params, W1t, W2t, W3t, (float*)d_out);
}

// Round 2
// 1210.766 us; speedup vs baseline: 1.0697x; 1.0697x over previous
//
#include <hip/hip_runtime.h>
#include <stdint.h>

#define E_TOT 500000
#define BM 64
#define NTHREADS 512

typedef float f32x4 __attribute__((ext_vector_type(4)));
typedef short short8 __attribute__((ext_vector_type(8)));

__device__ __forceinline__ float b2f(ushort u) {
    union { uint32_t i; float f; } v; v.i = ((uint32_t)u) << 16; return v.f;
}
__device__ __forceinline__ ushort f2b(float f) {
    union { float f; uint32_t i; } v; v.f = f;
    uint32_t r = (v.i + 0x7FFFu + ((v.i >> 16) & 1u)) >> 16;
    return (ushort)r;
}
__device__ __forceinline__ float ldf(const void* p, int i, int f32m) {
    return f32m ? ((const float*)p)[i] : b2f(((const ushort*)p)[i]);
}

// ---- format detection: flags[0]=1 if float inputs are f32, flags[1]=1 if batch is int64 ----
__global__ void detect_fmt(const void* src, const void* batch, int* flags) {
    __shared__ int s_ok, s_nz;
    if (threadIdx.x == 0) { s_ok = 0; s_nz = 0; }
    __syncthreads();
    int t = threadIdx.x;
    if (t < 64) {
        float f = fabsf(b2f(((const ushort*)src)[2 * t]));
        if (f > 1e-3f && f < 1e2f) atomicAdd(&s_ok, 1);
    }
    int hv = ((const int*)batch)[2 * t + 1];
    if (hv != 0) atomicOr(&s_nz, 1);
    __syncthreads();
    if (t == 0) { flags[0] = (s_ok < 32) ? 1 : 0; flags[1] = (s_nz == 0) ? 1 : 0; }
}

// ---- prep: transpose weights -> bf16 [N][K], convert small params -> f32 ----
__global__ void prep(const int* __restrict__ flags,
                     const void* W1, const void* W2, const void* W3,
                     const void* Ww, const void* bw, const void* gw, const void* bew,
                     const void* b1, const void* g1, const void* be1,
                     const void* b2, const void* g2, const void* be2, const void* b3,
                     ushort* __restrict__ W1t, ushort* __restrict__ W2t,
                     ushort* __restrict__ W3t, float* __restrict__ params) {
    int f32m = flags[0];
    int id = blockIdx.x * 256 + threadIdx.x;
    if (id < 98304) {                     // W1 [384][256] -> W1t [256][384]
        int k = id >> 8, n = id & 255;
        W1t[n * 384 + k] = f2b(ldf(W1, id, f32m));
    } else if (id < 163840) {             // W2 [256][256] -> W2t [256][256]
        int t = id - 98304; int k = t >> 8, n = t & 255;
        W2t[n * 256 + k] = f2b(ldf(W2, t, f32m));
    } else if (id < 180224) {             // W3 [256][64] -> W3t [64][256]
        int t = id - 163840; int k = t >> 6, n = t & 63;
        W3t[n * 256 + k] = f2b(ldf(W3, t, f32m));
    } else if (id < 182464) {             // params -> f32
        int p = id - 180224;
        const void* sp; int off;
        if      (p < 256)  { sp = Ww;  off = p; }
        else if (p < 384)  { sp = bw;  off = p - 256; }
        else if (p < 512)  { sp = gw;  off = p - 384; }
        else if (p < 640)  { sp = bew; off = p - 512; }
        else if (p < 896)  { sp = b1;  off = p - 640; }
        else if (p < 1152) { sp = g1;  off = p - 896; }
        else if (p < 1408) { sp = be1; off = p - 1152; }
        else if (p < 1664) { sp = b2;  off = p - 1408; }
        else if (p < 1920) { sp = g2;  off = p - 1664; }
        else if (p < 2176) { sp = be2; off = p - 1920; }
        else               { sp = b3;  off = p - 2176; }
        params[p] = ldf(sp, off, f32m);
    }
}

// Round-2 structure: BM=64 rows/block, 8 waves, each wave owns a 64x32 output strip
// -> acc[4][2] = 32 VGPRs (round-1's acc[4][4]=64 spilled under the 128-reg cap).
// Barrier-free K-loops (direct global B loads from L2-resident bf16 weights, direct
// global A loads in layer 1), single 32KB xh LDS buffer (winding -> h1 -> h2) with
// 16B-granule XOR swizzle. ~8 barriers/block; 2 blocks/CU co-resident.
__global__ __launch_bounds__(NTHREADS, 4) void fused_edge_mlp(
    const void* __restrict__ srcv, const void* __restrict__ destv,
    const void* __restrict__ eav, const void* __restrict__ uv,
    const int* __restrict__ bp, const void* __restrict__ windv,
    const int* __restrict__ flags, const float* __restrict__ params,
    const ushort* __restrict__ W1t, const ushort* __restrict__ W2t, const ushort* __restrict__ W3t,
    float* __restrict__ outp)
{
    __shared__ __align__(16) ushort xh[BM * 256];     // 32KB: winding(cols 0..127) -> h1 -> h2
    __shared__ float s_ww0[128], s_ww1[128], s_bw[128], s_gw[128], s_bew[128];
    __shared__ float s_b1[256], s_g1[256], s_be1[256];
    __shared__ float s_b2[256], s_g2[256], s_be2[256];
    __shared__ float s_b3[64];
    __shared__ int   s_uoff[BM];
    __shared__ float s_red1[BM * 8], s_red2[BM * 8];
    __shared__ float s_mu[BM], s_rs[BM];

    const int tid  = threadIdx.x;
    const int base = blockIdx.x * BM;
    const int f32m = flags[0];
    const int i64m = flags[1];

    // ---- stage small params + batch offsets to LDS (disjoint tid ranges) ----
    if (tid < 128) {
        s_ww0[tid] = params[tid];        s_ww1[tid] = params[128 + tid];
        s_bw[tid]  = params[256 + tid];  s_gw[tid]  = params[384 + tid];
        s_bew[tid] = params[512 + tid];
    } else if (tid < 384) {
        int j = tid - 128;
        s_b1[j] = params[640 + j];  s_g1[j] = params[896 + j];  s_be1[j] = params[1152 + j];
        s_b2[j] = params[1408 + j]; s_g2[j] = params[1664 + j]; s_be2[j] = params[1920 + j];
    } else if (tid < 448) {
        s_b3[tid - 384] = params[2176 + tid - 384];
    } else {
        int r = tid - 448;                               // 64 rows
        int gr = base + r; if (gr >= E_TOT) gr = E_TOT - 1;
        int bi = i64m ? bp[2 * gr] : bp[gr];
        s_uoff[r] = bi * 64;
    }
    __syncthreads();

    // ---- winding MLP: Linear(2->128) + LN + ReLU -> xh cols [0,128), swizzled bf16 ----
    {
        int r = tid >> 3, sub = tid & 7;                 // 8 threads/row, 16 outputs each
        int gr = base + r; if (gr >= E_TOT) gr = E_TOT - 1;
        float w0, w1;
        if (f32m) { const float* wp = (const float*)windv; w0 = wp[(long)gr * 2]; w1 = wp[(long)gr * 2 + 1]; }
        else      { const ushort* wp = (const ushort*)windv; w0 = b2f(wp[(long)gr * 2]); w1 = b2f(wp[(long)gr * 2 + 1]); }
        float s1 = 0.f, s2 = 0.f;
        float vv[16];
        #pragma unroll
        for (int j0 = 0; j0 < 16; ++j0) {
            int j = sub * 16 + j0;
            float t = fmaf(w0, s_ww0[j], fmaf(w1, s_ww1[j], s_bw[j]));
            vv[j0] = t; s1 += t; s2 += t * t;
        }
        s1 += __shfl_xor(s1, 1); s2 += __shfl_xor(s2, 1);
        s1 += __shfl_xor(s1, 2); s2 += __shfl_xor(s2, 2);
        s1 += __shfl_xor(s1, 4); s2 += __shfl_xor(s2, 4);
        float mu  = s1 * (1.f / 128.f);
        float var = s2 * (1.f / 128.f) - mu * mu;
        float rs  = rsqrtf(var + 1e-5f);
        #pragma unroll
        for (int j0 = 0; j0 < 16; ++j0) {
            int j = sub * 16 + j0;
            float t = (vv[j0] - mu) * rs * s_gw[j] + s_bew[j];
            xh[r * 256 + ((((j >> 3) ^ (r & 7))) << 3) + (j & 7)] = f2b(fmaxf(t, 0.f));
        }
    }
    __syncthreads();

    // ---- wave/lane geometry: wave wav owns rows 0..63 x cols [wav*32, wav*32+32) ----
    const int lane = tid & 63;
    const int wav  = tid >> 6;
    const int q    = lane >> 4, n16 = lane & 15;
    const int colbase = wav * 32;
    const int koff = q * 8;

    int grA[4], uofA[4];
    #pragma unroll
    for (int rt = 0; rt < 4; ++rt) {
        int row = rt * 16 + n16;
        int gr = base + row; if (gr >= E_TOT) gr = E_TOT - 1;
        grA[rt] = gr;
        uofA[rt] = s_uoff[row];
    }

    auto xh_frag = [&](int row, int colg) -> short8 {
        return *(const short8*)&xh[row * 256 + ((colg ^ (row & 7)) << 3)];
    };

    f32x4 acc[4][2];
    #pragma unroll
    for (int a = 0; a < 4; ++a)
        #pragma unroll
        for (int b = 0; b < 2; ++b) acc[a][b] = (f32x4){0.f, 0.f, 0.f, 0.f};

    // ---- Layer 1: x[64,384] @ W1 -> [64,256], no barriers ----
    if (!f32m) {
        #pragma unroll
        for (int kc = 0; kc < 8; ++kc) {
            const int grp = kc >> 1, off = (kc & 1) * 32 + koff;
            short8 afr[4], bfr[2];
            #pragma unroll
            for (int rt = 0; rt < 4; ++rt) {
                const ushort* ap;
                if      (grp == 0) ap = (const ushort*)srcv  + (long)grA[rt] * 64 + off;
                else if (grp == 1) ap = (const ushort*)destv + (long)grA[rt] * 64 + off;
                else if (grp == 2) ap = (const ushort*)eav   + (long)grA[rt] * 64 + off;
                else               ap = (const ushort*)uv    + uofA[rt] + off;
                afr[rt] = *(const short8*)ap;
            }
            #pragma unroll
            for (int ct = 0; ct < 2; ++ct)
                bfr[ct] = *(const short8*)(W1t + (colbase + ct * 16 + n16) * 384 + kc * 32 + koff);
            #pragma unroll
            for (int rt = 0; rt < 4; ++rt)
                #pragma unroll
                for (int ct = 0; ct < 2; ++ct)
                    acc[rt][ct] = __builtin_amdgcn_mfma_f32_16x16x32_bf16(afr[rt], bfr[ct], acc[rt][ct], 0, 0, 0);
        }
    } else {
        #pragma unroll
        for (int kc = 0; kc < 8; ++kc) {
            const int grp = kc >> 1, off = (kc & 1) * 32 + koff;
            short8 afr[4], bfr[2];
            #pragma unroll
            for (int rt = 0; rt < 4; ++rt) {
                const float* ap;
                if      (grp == 0) ap = (const float*)srcv  + (long)grA[rt] * 64 + off;
                else if (grp == 1) ap = (const float*)destv + (long)grA[rt] * 64 + off;
                else if (grp == 2) ap = (const float*)eav   + (long)grA[rt] * 64 + off;
                else               ap = (const float*)uv    + uofA[rt] + off;
                float4 x0 = *(const float4*)ap, x1 = *(const float4*)(ap + 4);
                union { short8 v; ushort s[8]; } pk;
                pk.s[0] = f2b(x0.x); pk.s[1] = f2b(x0.y); pk.s[2] = f2b(x0.z); pk.s[3] = f2b(x0.w);
                pk.s[4] = f2b(x1.x); pk.s[5] = f2b(x1.y); pk.s[6] = f2b(x1.z); pk.s[7] = f2b(x1.w);
                afr[rt] = pk.v;
            }
            #pragma unroll
            for (int ct = 0; ct < 2; ++ct)
                bfr[ct] = *(const short8*)(W1t + (colbase + ct * 16 + n16) * 384 + kc * 32 + koff);
            #pragma unroll
            for (int rt = 0; rt < 4; ++rt)
                #pragma unroll
                for (int ct = 0; ct < 2; ++ct)
                    acc[rt][ct] = __builtin_amdgcn_mfma_f32_16x16x32_bf16(afr[rt], bfr[ct], acc[rt][ct], 0, 0, 0);
        }
    }
    // winding columns of x (from LDS)
    #pragma unroll
    for (int kc = 8; kc < 12; ++kc) {
        short8 afr[4], bfr[2];
        #pragma unroll
        for (int rt = 0; rt < 4; ++rt) afr[rt] = xh_frag(rt * 16 + n16, (kc - 8) * 4 + q);
        #pragma unroll
        for (int ct = 0; ct < 2; ++ct)
            bfr[ct] = *(const short8*)(W1t + (colbase + ct * 16 + n16) * 384 + kc * 32 + koff);
        #pragma unroll
        for (int rt = 0; rt < 4; ++rt)
            #pragma unroll
            for (int ct = 0; ct < 2; ++ct)
                acc[rt][ct] = __builtin_amdgcn_mfma_f32_16x16x32_bf16(afr[rt], bfr[ct], acc[rt][ct], 0, 0, 0);
    }

    // ---- fused bias + LN + ReLU epilogue -> xh (swizzled bf16) ----
    auto ln_epilogue = [&](const float* bias, const float* gamma, const float* beta) {
        #pragma unroll
        for (int rt = 0; rt < 4; ++rt) {
            #pragma unroll
            for (int i = 0; i < 4; ++i) {
                float sv = 0.f, sq = 0.f;
                #pragma unroll
                for (int ct = 0; ct < 2; ++ct) {
                    float t = acc[rt][ct][i] + bias[colbase + ct * 16 + n16];
                    sv += t; sq += t * t;
                }
                #pragma unroll
                for (int m = 1; m < 16; m <<= 1) {
                    sv += __shfl_xor(sv, m); sq += __shfl_xor(sq, m);
                }
                if (n16 == 0) {
                    int row = rt * 16 + q * 4 + i;
                    s_red1[row * 8 + wav] = sv; s_red2[row * 8 + wav] = sq;
                }
            }
        }
        __syncthreads();
        if (tid < BM) {
            float sv = 0.f, sq = 0.f;
            #pragma unroll
            for (int c = 0; c < 8; ++c) { sv += s_red1[tid * 8 + c]; sq += s_red2[tid * 8 + c]; }
            float mu  = sv * (1.f / 256.f);
            float var = sq * (1.f / 256.f) - mu * mu;
            s_mu[tid] = mu; s_rs[tid] = rsqrtf(var + 1e-5f);
        }
        __syncthreads();
        #pragma unroll
        for (int rt = 0; rt < 4; ++rt) {
            #pragma unroll
            for (int ct = 0; ct < 2; ++ct) {
                int col = colbase + ct * 16 + n16;
                float bb = bias[col], gg = gamma[col], be = beta[col];
                #pragma unroll
                for (int i = 0; i < 4; ++i) {
                    int row = rt * 16 + q * 4 + i;
                    float t = acc[rt][ct][i] + bb;
                    t = (t - s_mu[row]) * s_rs[row] * gg + be;
                    xh[row * 256 + ((((col >> 3) ^ (row & 7))) << 3) + (col & 7)] = f2b(fmaxf(t, 0.f));
                }
            }
        }
        __syncthreads();
    };
    ln_epilogue(s_b1, s_g1, s_be1);

    // ---- Layer 2: h1[64,256] @ W2 -> [64,256], no barriers in loop ----
    #pragma unroll
    for (int a = 0; a < 4; ++a)
        #pragma unroll
        for (int b = 0; b < 2; ++b) acc[a][b] = (f32x4){0.f, 0.f, 0.f, 0.f};
    #pragma unroll
    for (int kc = 0; kc < 8; ++kc) {
        short8 afr[4], bfr[2];
        #pragma unroll
        for (int rt = 0; rt < 4; ++rt) afr[rt] = xh_frag(rt * 16 + n16, kc * 4 + q);
        #pragma unroll
        for (int ct = 0; ct < 2; ++ct)
            bfr[ct] = *(const short8*)(W2t + (colbase + ct * 16 + n16) * 256 + kc * 32 + koff);
        #pragma unroll
        for (int rt = 0; rt < 4; ++rt)
            #pragma unroll
            for (int ct = 0; ct < 2; ++ct)
                acc[rt][ct] = __builtin_amdgcn_mfma_f32_16x16x32_bf16(afr[rt], bfr[ct], acc[rt][ct], 0, 0, 0);
    }
    ln_epilogue(s_b2, s_g2, s_be2);   // h2 overwrites h1 (dead; barriers guard)

    // ---- Layer 3: h2[64,256] @ W3 -> out [64,64] (f32) ----
    // wave tile: 32 rows x 16 cols (rhalf = wav>>2, cg = wav&3)
    f32x4 acc3[2];
    #pragma unroll
    for (int a = 0; a < 2; ++a) acc3[a] = (f32x4){0.f, 0.f, 0.f, 0.f};
    const int rhalf = wav >> 2, cg = wav & 3;
    #pragma unroll
    for (int kc = 0; kc < 8; ++kc) {
        short8 b3f = *(const short8*)(W3t + (cg * 16 + n16) * 256 + kc * 32 + koff);
        #pragma unroll
        for (int rt = 0; rt < 2; ++rt) {
            short8 a3 = xh_frag(rhalf * 32 + rt * 16 + n16, kc * 4 + q);
            acc3[rt] = __builtin_amdgcn_mfma_f32_16x16x32_bf16(a3, b3f, acc3[rt], 0, 0, 0);
        }
    }
    #pragma unroll
    for (int rt = 0; rt < 2; ++rt) {
        int col = cg * 16 + n16;
        float bb = s_b3[col];
        #pragma unroll
        for (int i = 0; i < 4; ++i) {
            int row = rhalf * 32 + rt * 16 + q * 4 + i;
            int gr  = base + row;
            if (gr < E_TOT) outp[(long)gr * 64 + col] = acc3[rt][i] + bb;
        }
    }
}

extern "C" void kernel_launch(void* const* d_in, const int* in_sizes, int n_in,
                              void* d_out, int out_size, void* d_ws, size_t ws_size,
                              hipStream_t stream) {
    int*    flags  = (int*)d_ws;
    float*  params = (float*)((char*)d_ws + 16);
    ushort* W1t    = (ushort*)((char*)d_ws + 9216);     // [256][384]
    ushort* W2t    = W1t + 98304;                        // [256][256]
    ushort* W3t    = W2t + 65536;                        // [64][256]

    detect_fmt<<<1, 256, 0, stream>>>(d_in[0], d_in[4], flags);
    prep<<<713, 256, 0, stream>>>(flags,
        d_in[10], d_in[14], d_in[18],
        d_in[6], d_in[7], d_in[8], d_in[9],
        d_in[11], d_in[12], d_in[13],
        d_in[15], d_in[16], d_in[17], d_in[19],
        W1t, W2t, W3t, params);

    int nblocks = (E_TOT + BM - 1) / BM;   // 7813
    fused_edge_mlp<<<nblocks, NTHREADS, 0, stream>>>(
        d_in[0], d_in[1], d_in[2], d_in[3], (const int*)d_in[4], d_in[5],
        flags, params, W1t, W2t, W3t, (float*)d_out);
}